// Round 1
// 158.459 us; speedup vs baseline: 1.0144x; 1.0144x over previous
//
#include <hip/hip_runtime.h>

#define B_  8
#define L_  384
#define H_  512
#define NH_ 8
#define DH_ 64
#define RRM 768            // rproj rows computed; band uses [1,767]; +1 pad row

typedef short bf16x8 __attribute__((ext_vector_type(8)));
typedef float f32x4  __attribute__((ext_vector_type(4)));
typedef unsigned int u32;
typedef u32 u32x4 __attribute__((ext_vector_type(4)));
#define MFMA_BF16 __builtin_amdgcn_mfma_f32_16x16x32_bf16

static __device__ __forceinline__ unsigned short f2bf(float f) {
    unsigned u = __builtin_bit_cast(unsigned, f);
    u += 0x7fffu + ((u >> 16) & 1u);           // RNE
    return (unsigned short)(u >> 16);
}
static __device__ __forceinline__ float bf2f(unsigned short s) {
    unsigned u = ((unsigned)s) << 16;
    return __builtin_bit_cast(float, u);
}
// 2x f32 -> packed 2x bf16 (RNE), low half = lo. gfx950 has no builtin.
static __device__ __forceinline__ u32 pk2(float lo, float hi) {
    u32 r;
    asm("v_cvt_pk_bf16_f32 %0, %1, %2" : "=v"(r) : "v"(lo), "v"(hi));
    return r;
}

// ---------------------------------------------------------------------------
// bf16 MFMA NT GEMM, K=512, tile 64x64, BK=64, 4 waves (2x2 of 32x32).
// Staging: fp32 sources read into regs (2x float4/lane), converted with
// v_cvt_pk_bf16_f32, ds_write_b128 into the k8-slot XOR-swizzled layout
// LDS[r][s] = G[r][s ^ (r&7)] -> ds_read_b128 spreads over all 32 banks.
// This folds the old fp32->bf16 cvt pass into the GEMM (one fewer dispatch).
// Loads for kc+1 are issued before the barrier and consumed a full K-step
// later (issue-early / write-late), double-buffered, 1 barrier/iter.
// IS_FF=false: grid (8,48,4), z selects {q,k,v,pe} epilogues, A fp32.
// IS_FF=true : grid (8,48,1), A=Obf (bf16), W=Wff fp32, out = fp32 + bias.
// ---------------------------------------------------------------------------
template <bool IS_FF>
__global__ __launch_bounds__(256) void gemm_nt(
    const float* __restrict__ A0, const float* __restrict__ A1,
    const float* __restrict__ A2, const float* __restrict__ A3,
    const unsigned short* __restrict__ Abf,
    const float* __restrict__ W0, const float* __restrict__ W1,
    const float* __restrict__ W2, const float* __restrict__ W3,
    const float* __restrict__ W4,
    const float* __restrict__ b0, const float* __restrict__ b1,
    const float* __restrict__ b2, const float* __restrict__ b3,
    const float* __restrict__ b4,
    const float* __restrict__ ub, const float* __restrict__ vbias,
    unsigned short* __restrict__ qu, unsigned short* __restrict__ qv,
    unsigned short* __restrict__ kb, unsigned short* __restrict__ vT,
    unsigned short* __restrict__ rp, float* __restrict__ ff) {

    const int z = IS_FF ? 4 : blockIdx.z;
    if (!IS_FF && z == 3 && blockIdx.y >= 12) return;   // pe: 768 rows only
    const float* Af   = z == 0 ? A0 : z == 1 ? A1 : z == 2 ? A2 : A3;
    const float* W    = z == 0 ? W0 : z == 1 ? W1 : z == 2 ? W2 : z == 3 ? W3 : W4;
    const float* bias = z == 0 ? b0 : z == 1 ? b1 : z == 2 ? b2 : z == 3 ? b3 : b4;

    __shared__ __align__(16) unsigned short AsF[2 * 64 * 64];   // 16 KB
    __shared__ __align__(16) unsigned short BsF[2 * 64 * 64];

    const int tid = threadIdx.x;
    const int w = tid >> 6, lane = tid & 63;
    const int quad = lane >> 4, lm = lane & 15;
    const int wr = (w & 1) * 32, wc = (w >> 1) * 32;

    // staging roles: lane covers (row sr in an 8-row group, k8 slot sj);
    // global read is linear (slot sj), LDS write goes to slot sj ^ sr.
    const int sr = lane >> 3, sj = lane & 7;
    const size_t aoff = (size_t)(blockIdx.y * 64 + w * 16 + sr) * 512 + sj * 8;
    const size_t boff = (size_t)(blockIdx.x * 64 + w * 16 + sr) * 512 + sj * 8;

    f32x4 la[2][2], lb[2][2];
    bf16x8 lah[2];

    auto LOAD = [&](int kc) {
        #pragma unroll
        for (int t = 0; t < 2; ++t) {
            if constexpr (IS_FF) {
                lah[t] = *(const bf16x8*)(Abf + aoff + t * 8 * 512 + kc * 64);
            } else {
                const float* p = Af + aoff + t * 8 * 512 + kc * 64;
                la[t][0] = *(const f32x4*)p;
                la[t][1] = *(const f32x4*)(p + 4);
            }
            const float* q = W + boff + t * 8 * 512 + kc * 64;
            lb[t][0] = *(const f32x4*)q;
            lb[t][1] = *(const f32x4*)(q + 4);
        }
    };
    auto WRITE = [&](int buf) {
        #pragma unroll
        for (int t = 0; t < 2; ++t) {
            const int off = buf * 4096 + (w * 16 + t * 8 + sr) * 64 + (sj ^ sr) * 8;
            if constexpr (IS_FF) {
                *(bf16x8*)&AsF[off] = lah[t];
            } else {
                u32x4 pa;
                pa[0] = pk2(la[t][0][0], la[t][0][1]);
                pa[1] = pk2(la[t][0][2], la[t][0][3]);
                pa[2] = pk2(la[t][1][0], la[t][1][1]);
                pa[3] = pk2(la[t][1][2], la[t][1][3]);
                *(u32x4*)&AsF[off] = pa;
            }
            u32x4 pb;
            pb[0] = pk2(lb[t][0][0], lb[t][0][1]);
            pb[1] = pk2(lb[t][0][2], lb[t][0][3]);
            pb[2] = pk2(lb[t][1][0], lb[t][1][1]);
            pb[3] = pk2(lb[t][1][2], lb[t][1][3]);
            *(u32x4*)&BsF[off] = pb;
        }
    };

    f32x4 acc[2][2] = {};
    LOAD(0);
    #pragma unroll 2
    for (int kc = 0; kc < 8; ++kc) {
        const int buf = kc & 1;
        WRITE(buf);                            // waits vmcnt for LOAD(kc)
        if (kc < 7) LOAD(kc + 1);              // in flight across compute
        __syncthreads();
        const int base = buf * 4096;
        #pragma unroll
        for (int ks = 0; ks < 2; ++ks) {
            const int s = (((ks * 4 + quad) ^ (lm & 7))) * 8;  // swizzled slot
            bf16x8 a0 = *(const bf16x8*)&AsF[base + (wr + lm) * 64 + s];
            bf16x8 a1 = *(const bf16x8*)&AsF[base + (wr + 16 + lm) * 64 + s];
            bf16x8 w0 = *(const bf16x8*)&BsF[base + (wc + lm) * 64 + s];
            bf16x8 w1 = *(const bf16x8*)&BsF[base + (wc + 16 + lm) * 64 + s];
            acc[0][0] = MFMA_BF16(a0, w0, acc[0][0], 0, 0, 0);
            acc[0][1] = MFMA_BF16(a0, w1, acc[0][1], 0, 0, 0);
            acc[1][0] = MFMA_BF16(a1, w0, acc[1][0], 0, 0, 0);
            acc[1][1] = MFMA_BF16(a1, w1, acc[1][1], 0, 0, 0);
        }
    }

    #pragma unroll
    for (int si = 0; si < 2; ++si) {
        #pragma unroll
        for (int sj2 = 0; sj2 < 2; ++sj2) {
            #pragma unroll
            for (int reg = 0; reg < 4; ++reg) {
                const int r = blockIdx.y * 64 + wr + si * 16 + quad * 4 + reg;
                const int c = blockIdx.x * 64 + wc + sj2 * 16 + lm;
                const float val = acc[si][sj2][reg] + bias[c];
                if (IS_FF) {
                    ff[r * 512 + c] = val;
                } else if (z == 0) {
                    const int bb = r / L_, ii = r - bb * L_;
                    const int h = c >> 6, d = c & 63;
                    const int idx = ((bb * NH_ + h) * L_ + ii) * DH_ + d;
                    qu[idx] = f2bf((val + ub[c]) * 0.125f);     // pow2 scale: exact
                    qv[idx] = f2bf((val + vbias[c]) * 0.125f);
                } else if (z == 1) {
                    const int bb = r / L_, ii = r - bb * L_;
                    const int h = c >> 6, d = c & 63;
                    kb[((bb * NH_ + h) * L_ + ii) * DH_ + d] = f2bf(val);
                } else if (z == 2) {
                    const int bb = r / L_, ii = r - bb * L_;
                    const int h = c >> 6, d = c & 63;
                    vT[((bb * NH_ + h) * DH_ + d) * L_ + ii] = f2bf(val);
                } else {
                    rp[r * 512 + c] = f2bf(val);
                }
            }
        }
    }
}

// ---------------------------------------------------------------------------
// Fully fused attention per (bh, 32-row i-tile)  [unchanged]
// ---------------------------------------------------------------------------
#define BTSTR 424
__global__ __launch_bounds__(256) void attn_fused(
    const unsigned short* __restrict__ qu, const unsigned short* __restrict__ qv,
    const unsigned short* __restrict__ kbf, const unsigned short* __restrict__ vT,
    const unsigned short* __restrict__ rp, const int* __restrict__ seq_len,
    unsigned short* __restrict__ Obf) {
    __shared__ __align__(16) unsigned short BtP[32 * BTSTR];
    __shared__ float mx_red[32][2];
    __shared__ float sm_red[32][2];
    const int lane = threadIdx.x & 63, wv = threadIdx.x >> 6;
    const int quad = lane >> 4, lm = lane & 15;
    const int bh = blockIdx.y, b = bh >> 3, h = bh & 7;
    const int i0 = blockIdx.x * 32;
    const int sl = seq_len[b];
    const int msub = wv & 1, nh = wv >> 1;
    const int m_lo = 353 - i0;
    const int i_fr = i0 + msub * 16 + lm;

    {
        const unsigned short* qvr = qv + (size_t)(bh * L_ + i_fr) * DH_;
        const bf16x8 av0 = *(const bf16x8*)(qvr + quad * 8);
        const bf16x8 av1 = *(const bf16x8*)(qvr + 32 + quad * 8);
        #pragma unroll
        for (int ns = 0; ns < 13; ++ns) {
            const int ntl = nh * 208 + ns * 16;
            if (ntl <= sl + 30) {
                const int n = ntl + lm;
                const unsigned short* rrow = rp + (size_t)(m_lo + n) * 512 + h * 64;
                f32x4 bacc = {};
                bacc = MFMA_BF16(av0, *(const bf16x8*)(rrow + quad * 8), bacc, 0, 0, 0);
                bacc = MFMA_BF16(av1, *(const bf16x8*)(rrow + 32 + quad * 8), bacc, 0, 0, 0);
                #pragma unroll
                for (int reg = 0; reg < 4; ++reg) {
                    const int il = msub * 16 + quad * 4 + reg;
                    BtP[il * BTSTR + n] = f2bf(bacc[reg]);
                }
            }
        }
    }
    const unsigned short* qur = qu + (size_t)(bh * L_ + i_fr) * DH_;
    const bf16x8 au0 = *(const bf16x8*)(qur + quad * 8);
    const bf16x8 au1 = *(const bf16x8*)(qur + 32 + quad * 8);
    __syncthreads();

    f32x4 sc[12];
    #pragma unroll
    for (int ns = 0; ns < 12; ++ns) {
        const int jt = nh * 192 + ns * 16;
        if (jt < sl) {
            const unsigned short* krow = kbf + (size_t)(bh * L_ + jt + lm) * DH_;
            f32x4 a = {};
            a = MFMA_BF16(au0, *(const bf16x8*)(krow + quad * 8), a, 0, 0, 0);
            a = MFMA_BF16(au1, *(const bf16x8*)(krow + 32 + quad * 8), a, 0, 0, 0);
            sc[ns] = a;
        } else {
            sc[ns] = f32x4{-1e30f, -1e30f, -1e30f, -1e30f};
        }
    }
    const int jbase = nh * 192 + lm;
    #pragma unroll
    for (int ns = 0; ns < 12; ++ns) {
        const int j = jbase + ns * 16;
        #pragma unroll
        for (int reg = 0; reg < 4; ++reg) {
            const int il = msub * 16 + quad * 4 + reg;
            float val = -1e30f;
            if (j < sl) val = sc[ns][reg] + bf2f(BtP[il * BTSTR + (j - il + 31)]);
            sc[ns][reg] = val;
        }
    }

    const int il0 = msub * 16 + quad * 4;
    float mx4[4], sm4[4], inv4[4];
    #pragma unroll
    for (int reg = 0; reg < 4; ++reg) {
        float m = sc[0][reg];
        #pragma unroll
        for (int ns = 1; ns < 12; ++ns) m = fmaxf(m, sc[ns][reg]);
        #pragma unroll
        for (int o = 1; o < 16; o <<= 1) m = fmaxf(m, __shfl_xor(m, o));
        mx4[reg] = m;
    }
    if (lm == 0) {
        #pragma unroll
        for (int reg = 0; reg < 4; ++reg) mx_red[il0 + reg][nh] = mx4[reg];
    }
    __syncthreads();
    #pragma unroll
    for (int reg = 0; reg < 4; ++reg)
        mx4[reg] = fmaxf(mx_red[il0 + reg][0], mx_red[il0 + reg][1]);
    #pragma unroll
    for (int reg = 0; reg < 4; ++reg) sm4[reg] = 0.f;
    #pragma unroll
    for (int ns = 0; ns < 12; ++ns) {
        #pragma unroll
        for (int reg = 0; reg < 4; ++reg) {
            const float e = __expf(sc[ns][reg] - mx4[reg]);
            sc[ns][reg] = e;
            sm4[reg] += e;
        }
    }
    #pragma unroll
    for (int reg = 0; reg < 4; ++reg) {
        float s = sm4[reg];
        #pragma unroll
        for (int o = 1; o < 16; o <<= 1) s += __shfl_xor(s, o);
        sm4[reg] = s;
    }
    if (lm == 0) {
        #pragma unroll
        for (int reg = 0; reg < 4; ++reg) sm_red[il0 + reg][nh] = sm4[reg];
    }
    __syncthreads();
    #pragma unroll
    for (int reg = 0; reg < 4; ++reg)
        inv4[reg] = 1.f / (sm_red[il0 + reg][0] + sm_red[il0 + reg][1]);

    #pragma unroll
    for (int ns = 0; ns < 12; ++ns) {
        const int j = jbase + ns * 16;
        #pragma unroll
        for (int reg = 0; reg < 4; ++reg)
            BtP[(il0 + reg) * BTSTR + j] = f2bf(sc[ns][reg] * inv4[reg]);
    }
    __syncthreads();

    {
        const int pr = msub * 16 + lm;
        const int nkc = (sl + 31) >> 5;
        f32x4 oacc[2] = {};
        for (int kc = 0; kc < nkc; ++kc) {
            const bf16x8 af = *(const bf16x8*)&BtP[pr * BTSTR + kc * 32 + quad * 8];
            #pragma unroll
            for (int t = 0; t < 2; ++t) {
                const int n = nh * 32 + t * 16 + lm;
                const unsigned short* vrow = vT + (size_t)(bh * DH_ + n) * L_ + kc * 32 + quad * 8;
                oacc[t] = MFMA_BF16(af, *(const bf16x8*)(vrow), oacc[t], 0, 0, 0);
            }
        }
        #pragma unroll
        for (int t = 0; t < 2; ++t) {
            #pragma unroll
            for (int reg = 0; reg < 4; ++reg) {
                const int i = i0 + msub * 16 + quad * 4 + reg;
                const int d = nh * 32 + t * 16 + lm;
                Obf[(size_t)(b * L_ + i) * H_ + h * DH_ + d] = f2bf(oacc[t][reg]);
            }
        }
    }
}

extern "C" void kernel_launch(void* const* d_in, const int* in_sizes, int n_in,
                              void* d_out, int out_size, void* d_ws, size_t ws_size,
                              hipStream_t stream) {
    const float* key    = (const float*)d_in[0];
    const float* query  = (const float*)d_in[1];
    const float* value  = (const float*)d_in[2];
    const int*   seqlen = (const int*)d_in[3];
    const float* pe     = (const float*)d_in[4];
    const float* Wk     = (const float*)d_in[5];
    const float* bk     = (const float*)d_in[6];
    const float* Wq     = (const float*)d_in[7];
    const float* bq     = (const float*)d_in[8];
    const float* Wv     = (const float*)d_in[9];
    const float* bv     = (const float*)d_in[10];
    const float* Wr     = (const float*)d_in[11];
    const float* br     = (const float*)d_in[12];
    const float* u_bias = (const float*)d_in[13];
    const float* v_bias = (const float*)d_in[14];
    const float* Wff    = (const float*)d_in[15];
    const float* bff    = (const float*)d_in[16];

    const size_t nTok = (size_t)B_ * L_ * H_;    // 1,572,864
    const size_t nPe  = (size_t)RRM * H_;        // 393,216
    unsigned short* p  = (unsigned short*)d_ws;
    unsigned short* qu   = p; p += nTok;
    unsigned short* qv   = p; p += nTok;
    unsigned short* kb   = p; p += nTok;
    unsigned short* vT   = p; p += nTok;
    unsigned short* rp   = p; p += nPe + 512;    // +1 pad row (corner n=415, never read back)
    unsigned short* Obf  = p; p += nTok;

    // projections (fp32 inputs converted in-staging): u/v biases + 1/8 scale
    // folded into q epilogue
    gemm_nt<false><<<dim3(8, 48, 4), 256, 0, stream>>>(
        /*A0..A3 fp32*/ query, key, value, pe, /*Abf*/ nullptr,
        /*W0..W4 fp32*/ Wq, Wk, Wv, Wr, nullptr,
        /*b0..b4*/ bq, bk, bv, br, nullptr,
        /*ub,vbias*/ u_bias, v_bias,
        /*qu,qv,kb,vT,rp*/ qu, qv, kb, vT, rp,
        /*ff*/ nullptr);

    // fused Bt + scores + softmax + PV
    attn_fused<<<dim3(L_ / 32, B_ * NH_), 256, 0, stream>>>(
        qu, qv, kb, vT, rp, seqlen, Obf);

    // output projection
    gemm_nt<true><<<dim3(8, 48, 1), 256, 0, stream>>>(
        /*A0..A3*/ nullptr, nullptr, nullptr, nullptr, /*Abf*/ Obf,
        /*W0..W4*/ nullptr, nullptr, nullptr, nullptr, Wff,
        /*b0..b4*/ nullptr, nullptr, nullptr, nullptr, bff,
        /*ub,vbias*/ nullptr, nullptr,
        /*qu,qv,kb,vT,rp*/ nullptr, nullptr, nullptr, nullptr, nullptr,
        /*ff*/ (float*)d_out);
}

// Round 2
// 155.774 us; speedup vs baseline: 1.0318x; 1.0172x over previous
//
#include <hip/hip_runtime.h>

#define B_  8
#define L_  384
#define H_  512
#define NH_ 8
#define DH_ 64
#define RRM 768            // rproj rows computed; band uses [1,767]; +1 pad row

typedef short bf16x8 __attribute__((ext_vector_type(8)));
typedef float f32x4  __attribute__((ext_vector_type(4)));
typedef unsigned int u32;
typedef u32 u32x4 __attribute__((ext_vector_type(4)));
#define MFMA_BF16 __builtin_amdgcn_mfma_f32_16x16x32_bf16

static __device__ __forceinline__ unsigned short f2bf(float f) {
    unsigned u = __builtin_bit_cast(unsigned, f);
    u += 0x7fffu + ((u >> 16) & 1u);           // RNE
    return (unsigned short)(u >> 16);
}
static __device__ __forceinline__ float bf2f(unsigned short s) {
    unsigned u = ((unsigned)s) << 16;
    return __builtin_bit_cast(float, u);
}
// 2x f32 -> packed 2x bf16 (RNE), low half = lo. gfx950 has no builtin.
static __device__ __forceinline__ u32 pk2(float lo, float hi) {
    u32 r;
    asm("v_cvt_pk_bf16_f32 %0, %1, %2" : "=v"(r) : "v"(lo), "v"(hi));
    return r;
}

// ---------------------------------------------------------------------------
// bf16 MFMA NT GEMM, K=512, tile 64x128, BK=64, 4 waves (each 32 rows x 64
// cols, acc[2][4] -> 16 MFMA per K-step per wave, double the old 64x64 tile's
// MFMA-per-barrier ratio).
// Staging: fp32 sources read into regs (float4 pairs), converted with
// v_cvt_pk_bf16_f32, ds_write_b128 into the k8-slot XOR-swizzled layout
// LDS[r][s] = G[r][s ^ (r&7)] -> ds_read_b128 spreads over all 32 banks.
// Loads for kc+1 issued before the barrier, consumed a K-step later
// (issue-early / write-late), double-buffered, 1 barrier/iter.
// IS_FF=false: grid (4,48,4), z selects {q,k,v,pe} epilogues, A fp32.
// IS_FF=true : grid (4,48,1), A=Obf (bf16), W=Wff fp32, out = fp32 + bias.
// ---------------------------------------------------------------------------
template <bool IS_FF>
__global__ __launch_bounds__(256) void gemm_nt(
    const float* __restrict__ A0, const float* __restrict__ A1,
    const float* __restrict__ A2, const float* __restrict__ A3,
    const unsigned short* __restrict__ Abf,
    const float* __restrict__ W0, const float* __restrict__ W1,
    const float* __restrict__ W2, const float* __restrict__ W3,
    const float* __restrict__ W4,
    const float* __restrict__ b0, const float* __restrict__ b1,
    const float* __restrict__ b2, const float* __restrict__ b3,
    const float* __restrict__ b4,
    const float* __restrict__ ub, const float* __restrict__ vbias,
    unsigned short* __restrict__ qu, unsigned short* __restrict__ qv,
    unsigned short* __restrict__ kb, unsigned short* __restrict__ vT,
    unsigned short* __restrict__ rp, float* __restrict__ ff) {

    const int z = IS_FF ? 4 : blockIdx.z;
    if (!IS_FF && z == 3 && blockIdx.y >= 12) return;   // pe: 768 rows only
    const float* Af   = z == 0 ? A0 : z == 1 ? A1 : z == 2 ? A2 : A3;
    const float* W    = z == 0 ? W0 : z == 1 ? W1 : z == 2 ? W2 : z == 3 ? W3 : W4;
    const float* bias = z == 0 ? b0 : z == 1 ? b1 : z == 2 ? b2 : z == 3 ? b3 : b4;

    __shared__ __align__(16) unsigned short AsF[2 * 64 * 64];    // 16 KB
    __shared__ __align__(16) unsigned short BsF[2 * 128 * 64];   // 32 KB

    const int tid = threadIdx.x;
    const int w = tid >> 6, lane = tid & 63;
    const int quad = lane >> 4, lm = lane & 15;
    const int wr = (w & 1) * 32;          // wave row offset (A: 64 rows, 2x32)
    const int wc = (w >> 1) * 64;         // wave col offset (B: 128 rows, 2x64)

    // staging roles: lane covers (row sr in an 8-row group, k8 slot sj);
    // global read is linear (slot sj), LDS write goes to slot sj ^ sr.
    const int sr = lane >> 3, sj = lane & 7;
    const size_t aoff = (size_t)(blockIdx.y * 64 + w * 16 + sr) * 512 + sj * 8;
    const size_t boff = (size_t)(blockIdx.x * 128 + w * 32 + sr) * 512 + sj * 8;

    f32x4 la[2][2], lb[4][2];
    bf16x8 lah[2];

    auto LOAD = [&](int kc) {
        #pragma unroll
        for (int t = 0; t < 2; ++t) {
            if constexpr (IS_FF) {
                lah[t] = *(const bf16x8*)(Abf + aoff + t * 8 * 512 + kc * 64);
            } else {
                const float* p = Af + aoff + t * 8 * 512 + kc * 64;
                la[t][0] = *(const f32x4*)p;
                la[t][1] = *(const f32x4*)(p + 4);
            }
        }
        #pragma unroll
        for (int t = 0; t < 4; ++t) {
            const float* q = W + boff + t * 8 * 512 + kc * 64;
            lb[t][0] = *(const f32x4*)q;
            lb[t][1] = *(const f32x4*)(q + 4);
        }
    };
    auto WRITE = [&](int buf) {
        #pragma unroll
        for (int t = 0; t < 2; ++t) {
            const int off = buf * 4096 + (w * 16 + t * 8 + sr) * 64 + (sj ^ sr) * 8;
            if constexpr (IS_FF) {
                *(bf16x8*)&AsF[off] = lah[t];
            } else {
                u32x4 pa;
                pa[0] = pk2(la[t][0][0], la[t][0][1]);
                pa[1] = pk2(la[t][0][2], la[t][0][3]);
                pa[2] = pk2(la[t][1][0], la[t][1][1]);
                pa[3] = pk2(la[t][1][2], la[t][1][3]);
                *(u32x4*)&AsF[off] = pa;
            }
        }
        #pragma unroll
        for (int t = 0; t < 4; ++t) {
            const int off = buf * 8192 + (w * 32 + t * 8 + sr) * 64 + (sj ^ sr) * 8;
            u32x4 pb;
            pb[0] = pk2(lb[t][0][0], lb[t][0][1]);
            pb[1] = pk2(lb[t][0][2], lb[t][0][3]);
            pb[2] = pk2(lb[t][1][0], lb[t][1][1]);
            pb[3] = pk2(lb[t][1][2], lb[t][1][3]);
            *(u32x4*)&BsF[off] = pb;
        }
    };

    f32x4 acc[2][4] = {};
    LOAD(0);
    for (int kc = 0; kc < 8; ++kc) {
        const int buf = kc & 1;
        WRITE(buf);                            // waits vmcnt for LOAD(kc)
        if (kc < 7) LOAD(kc + 1);              // in flight across compute
        __syncthreads();
        const int ba = buf * 4096, bb = buf * 8192;
        #pragma unroll
        for (int ks = 0; ks < 2; ++ks) {
            const int s = (((ks * 4 + quad) ^ (lm & 7))) * 8;  // swizzled slot
            bf16x8 a0 = *(const bf16x8*)&AsF[ba + (wr + lm) * 64 + s];
            bf16x8 a1 = *(const bf16x8*)&AsF[ba + (wr + 16 + lm) * 64 + s];
            bf16x8 w0 = *(const bf16x8*)&BsF[bb + (wc + lm) * 64 + s];
            bf16x8 w1 = *(const bf16x8*)&BsF[bb + (wc + 16 + lm) * 64 + s];
            bf16x8 w2 = *(const bf16x8*)&BsF[bb + (wc + 32 + lm) * 64 + s];
            bf16x8 w3 = *(const bf16x8*)&BsF[bb + (wc + 48 + lm) * 64 + s];
            acc[0][0] = MFMA_BF16(a0, w0, acc[0][0], 0, 0, 0);
            acc[0][1] = MFMA_BF16(a0, w1, acc[0][1], 0, 0, 0);
            acc[0][2] = MFMA_BF16(a0, w2, acc[0][2], 0, 0, 0);
            acc[0][3] = MFMA_BF16(a0, w3, acc[0][3], 0, 0, 0);
            acc[1][0] = MFMA_BF16(a1, w0, acc[1][0], 0, 0, 0);
            acc[1][1] = MFMA_BF16(a1, w1, acc[1][1], 0, 0, 0);
            acc[1][2] = MFMA_BF16(a1, w2, acc[1][2], 0, 0, 0);
            acc[1][3] = MFMA_BF16(a1, w3, acc[1][3], 0, 0, 0);
        }
        __syncthreads();                       // buf reusable next iter
    }

    #pragma unroll
    for (int si = 0; si < 2; ++si) {
        #pragma unroll
        for (int sj2 = 0; sj2 < 4; ++sj2) {
            #pragma unroll
            for (int reg = 0; reg < 4; ++reg) {
                const int r = blockIdx.y * 64 + wr + si * 16 + quad * 4 + reg;
                const int c = blockIdx.x * 128 + wc + sj2 * 16 + lm;
                const float val = acc[si][sj2][reg] + bias[c];
                if (IS_FF) {
                    ff[r * 512 + c] = val;
                } else if (z == 0) {
                    const int bb2 = r / L_, ii = r - bb2 * L_;
                    const int h = c >> 6, d = c & 63;
                    const int idx = ((bb2 * NH_ + h) * L_ + ii) * DH_ + d;
                    qu[idx] = f2bf((val + ub[c]) * 0.125f);     // pow2 scale: exact
                    qv[idx] = f2bf((val + vbias[c]) * 0.125f);
                } else if (z == 1) {
                    const int bb2 = r / L_, ii = r - bb2 * L_;
                    const int h = c >> 6, d = c & 63;
                    kb[((bb2 * NH_ + h) * L_ + ii) * DH_ + d] = f2bf(val);
                } else if (z == 2) {
                    const int bb2 = r / L_, ii = r - bb2 * L_;
                    const int h = c >> 6, d = c & 63;
                    vT[((bb2 * NH_ + h) * DH_ + d) * L_ + ii] = f2bf(val);
                } else {
                    rp[r * 512 + c] = f2bf(val);
                }
            }
        }
    }
}

// ---------------------------------------------------------------------------
// Fully fused attention per (bh, 32-row i-tile)  [unchanged]
// ---------------------------------------------------------------------------
#define BTSTR 424
__global__ __launch_bounds__(256) void attn_fused(
    const unsigned short* __restrict__ qu, const unsigned short* __restrict__ qv,
    const unsigned short* __restrict__ kbf, const unsigned short* __restrict__ vT,
    const unsigned short* __restrict__ rp, const int* __restrict__ seq_len,
    unsigned short* __restrict__ Obf) {
    __shared__ __align__(16) unsigned short BtP[32 * BTSTR];
    __shared__ float mx_red[32][2];
    __shared__ float sm_red[32][2];
    const int lane = threadIdx.x & 63, wv = threadIdx.x >> 6;
    const int quad = lane >> 4, lm = lane & 15;
    const int bh = blockIdx.y, b = bh >> 3, h = bh & 7;
    const int i0 = blockIdx.x * 32;
    const int sl = seq_len[b];
    const int msub = wv & 1, nh = wv >> 1;
    const int m_lo = 353 - i0;
    const int i_fr = i0 + msub * 16 + lm;

    {
        const unsigned short* qvr = qv + (size_t)(bh * L_ + i_fr) * DH_;
        const bf16x8 av0 = *(const bf16x8*)(qvr + quad * 8);
        const bf16x8 av1 = *(const bf16x8*)(qvr + 32 + quad * 8);
        #pragma unroll
        for (int ns = 0; ns < 13; ++ns) {
            const int ntl = nh * 208 + ns * 16;
            if (ntl <= sl + 30) {
                const int n = ntl + lm;
                const unsigned short* rrow = rp + (size_t)(m_lo + n) * 512 + h * 64;
                f32x4 bacc = {};
                bacc = MFMA_BF16(av0, *(const bf16x8*)(rrow + quad * 8), bacc, 0, 0, 0);
                bacc = MFMA_BF16(av1, *(const bf16x8*)(rrow + 32 + quad * 8), bacc, 0, 0, 0);
                #pragma unroll
                for (int reg = 0; reg < 4; ++reg) {
                    const int il = msub * 16 + quad * 4 + reg;
                    BtP[il * BTSTR + n] = f2bf(bacc[reg]);
                }
            }
        }
    }
    const unsigned short* qur = qu + (size_t)(bh * L_ + i_fr) * DH_;
    const bf16x8 au0 = *(const bf16x8*)(qur + quad * 8);
    const bf16x8 au1 = *(const bf16x8*)(qur + 32 + quad * 8);
    __syncthreads();

    f32x4 sc[12];
    #pragma unroll
    for (int ns = 0; ns < 12; ++ns) {
        const int jt = nh * 192 + ns * 16;
        if (jt < sl) {
            const unsigned short* krow = kbf + (size_t)(bh * L_ + jt + lm) * DH_;
            f32x4 a = {};
            a = MFMA_BF16(au0, *(const bf16x8*)(krow + quad * 8), a, 0, 0, 0);
            a = MFMA_BF16(au1, *(const bf16x8*)(krow + 32 + quad * 8), a, 0, 0, 0);
            sc[ns] = a;
        } else {
            sc[ns] = f32x4{-1e30f, -1e30f, -1e30f, -1e30f};
        }
    }
    const int jbase = nh * 192 + lm;
    #pragma unroll
    for (int ns = 0; ns < 12; ++ns) {
        const int j = jbase + ns * 16;
        #pragma unroll
        for (int reg = 0; reg < 4; ++reg) {
            const int il = msub * 16 + quad * 4 + reg;
            float val = -1e30f;
            if (j < sl) val = sc[ns][reg] + bf2f(BtP[il * BTSTR + (j - il + 31)]);
            sc[ns][reg] = val;
        }
    }

    const int il0 = msub * 16 + quad * 4;
    float mx4[4], sm4[4], inv4[4];
    #pragma unroll
    for (int reg = 0; reg < 4; ++reg) {
        float m = sc[0][reg];
        #pragma unroll
        for (int ns = 1; ns < 12; ++ns) m = fmaxf(m, sc[ns][reg]);
        #pragma unroll
        for (int o = 1; o < 16; o <<= 1) m = fmaxf(m, __shfl_xor(m, o));
        mx4[reg] = m;
    }
    if (lm == 0) {
        #pragma unroll
        for (int reg = 0; reg < 4; ++reg) mx_red[il0 + reg][nh] = mx4[reg];
    }
    __syncthreads();
    #pragma unroll
    for (int reg = 0; reg < 4; ++reg)
        mx4[reg] = fmaxf(mx_red[il0 + reg][0], mx_red[il0 + reg][1]);
    #pragma unroll
    for (int reg = 0; reg < 4; ++reg) sm4[reg] = 0.f;
    #pragma unroll
    for (int ns = 0; ns < 12; ++ns) {
        #pragma unroll
        for (int reg = 0; reg < 4; ++reg) {
            const float e = __expf(sc[ns][reg] - mx4[reg]);
            sc[ns][reg] = e;
            sm4[reg] += e;
        }
    }
    #pragma unroll
    for (int reg = 0; reg < 4; ++reg) {
        float s = sm4[reg];
        #pragma unroll
        for (int o = 1; o < 16; o <<= 1) s += __shfl_xor(s, o);
        sm4[reg] = s;
    }
    if (lm == 0) {
        #pragma unroll
        for (int reg = 0; reg < 4; ++reg) sm_red[il0 + reg][nh] = sm4[reg];
    }
    __syncthreads();
    #pragma unroll
    for (int reg = 0; reg < 4; ++reg)
        inv4[reg] = 1.f / (sm_red[il0 + reg][0] + sm_red[il0 + reg][1]);

    #pragma unroll
    for (int ns = 0; ns < 12; ++ns) {
        const int j = jbase + ns * 16;
        #pragma unroll
        for (int reg = 0; reg < 4; ++reg)
            BtP[(il0 + reg) * BTSTR + j] = f2bf(sc[ns][reg] * inv4[reg]);
    }
    __syncthreads();

    {
        const int pr = msub * 16 + lm;
        const int nkc = (sl + 31) >> 5;
        f32x4 oacc[2] = {};
        for (int kc = 0; kc < nkc; ++kc) {
            const bf16x8 af = *(const bf16x8*)&BtP[pr * BTSTR + kc * 32 + quad * 8];
            #pragma unroll
            for (int t = 0; t < 2; ++t) {
                const int n = nh * 32 + t * 16 + lm;
                const unsigned short* vrow = vT + (size_t)(bh * DH_ + n) * L_ + kc * 32 + quad * 8;
                oacc[t] = MFMA_BF16(af, *(const bf16x8*)(vrow), oacc[t], 0, 0, 0);
            }
        }
        #pragma unroll
        for (int t = 0; t < 2; ++t) {
            #pragma unroll
            for (int reg = 0; reg < 4; ++reg) {
                const int i = i0 + msub * 16 + quad * 4 + reg;
                const int d = nh * 32 + t * 16 + lm;
                Obf[(size_t)(b * L_ + i) * H_ + h * DH_ + d] = f2bf(oacc[t][reg]);
            }
        }
    }
}

extern "C" void kernel_launch(void* const* d_in, const int* in_sizes, int n_in,
                              void* d_out, int out_size, void* d_ws, size_t ws_size,
                              hipStream_t stream) {
    const float* key    = (const float*)d_in[0];
    const float* query  = (const float*)d_in[1];
    const float* value  = (const float*)d_in[2];
    const int*   seqlen = (const int*)d_in[3];
    const float* pe     = (const float*)d_in[4];
    const float* Wk     = (const float*)d_in[5];
    const float* bk     = (const float*)d_in[6];
    const float* Wq     = (const float*)d_in[7];
    const float* bq     = (const float*)d_in[8];
    const float* Wv     = (const float*)d_in[9];
    const float* bv     = (const float*)d_in[10];
    const float* Wr     = (const float*)d_in[11];
    const float* br     = (const float*)d_in[12];
    const float* u_bias = (const float*)d_in[13];
    const float* v_bias = (const float*)d_in[14];
    const float* Wff    = (const float*)d_in[15];
    const float* bff    = (const float*)d_in[16];

    const size_t nTok = (size_t)B_ * L_ * H_;    // 1,572,864
    const size_t nPe  = (size_t)RRM * H_;        // 393,216
    unsigned short* p  = (unsigned short*)d_ws;
    unsigned short* qu   = p; p += nTok;
    unsigned short* qv   = p; p += nTok;
    unsigned short* kb   = p; p += nTok;
    unsigned short* vT   = p; p += nTok;
    unsigned short* rp   = p; p += nPe + 512;    // +1 pad row (corner n=415, never read back)
    unsigned short* Obf  = p; p += nTok;

    // projections (fp32 inputs converted in-staging): u/v biases + 1/8 scale
    // folded into q epilogue
    gemm_nt<false><<<dim3(4, 48, 4), 256, 0, stream>>>(
        /*A0..A3 fp32*/ query, key, value, pe, /*Abf*/ nullptr,
        /*W0..W4 fp32*/ Wq, Wk, Wv, Wr, nullptr,
        /*b0..b4*/ bq, bk, bv, br, nullptr,
        /*ub,vbias*/ u_bias, v_bias,
        /*qu,qv,kb,vT,rp*/ qu, qv, kb, vT, rp,
        /*ff*/ nullptr);

    // fused Bt + scores + softmax + PV
    attn_fused<<<dim3(L_ / 32, B_ * NH_), 256, 0, stream>>>(
        qu, qv, kb, vT, rp, seqlen, Obf);

    // output projection
    gemm_nt<true><<<dim3(4, 48, 1), 256, 0, stream>>>(
        /*A0..A3*/ nullptr, nullptr, nullptr, nullptr, /*Abf*/ Obf,
        /*W0..W4*/ nullptr, nullptr, nullptr, nullptr, Wff,
        /*b0..b4*/ nullptr, nullptr, nullptr, nullptr, bff,
        /*ub,vbias*/ nullptr, nullptr,
        /*qu,qv,kb,vT,rp*/ nullptr, nullptr, nullptr, nullptr, nullptr,
        /*ff*/ (float*)d_out);
}

// Round 3
// 152.276 us; speedup vs baseline: 1.0555x; 1.0230x over previous
//
#include <hip/hip_runtime.h>

#define B_  8
#define L_  384
#define H_  512
#define NH_ 8
#define DH_ 64
#define RRM 768            // rproj rows computed; band uses [1,767]; +1 pad row

typedef short bf16x8 __attribute__((ext_vector_type(8)));
typedef float f32x4  __attribute__((ext_vector_type(4)));
typedef unsigned int u32;
typedef u32 u32x4 __attribute__((ext_vector_type(4)));
#define MFMA_BF16 __builtin_amdgcn_mfma_f32_16x16x32_bf16

static __device__ __forceinline__ unsigned short f2bf(float f) {
    unsigned u = __builtin_bit_cast(unsigned, f);
    u += 0x7fffu + ((u >> 16) & 1u);           // RNE
    return (unsigned short)(u >> 16);
}
static __device__ __forceinline__ float bf2f(unsigned short s) {
    unsigned u = ((unsigned)s) << 16;
    return __builtin_bit_cast(float, u);
}
// 2x f32 -> packed 2x bf16 (RNE), low half = lo. gfx950 has no builtin.
static __device__ __forceinline__ u32 pk2(float lo, float hi) {
    u32 r;
    asm("v_cvt_pk_bf16_f32 %0, %1, %2" : "=v"(r) : "v"(lo), "v"(hi));
    return r;
}
// async 16 B/lane global->LDS DMA (gfx950). LDS dest = wave-uniform base +
// lane*16; caller guarantees the base is wave-uniform (readfirstlane'd).
static __device__ __forceinline__ void glds16(const void* g, void* l) {
    __builtin_amdgcn_global_load_lds(
        (const __attribute__((address_space(1))) u32*)g,
        (__attribute__((address_space(3))) u32*)l, 16, 0, 0);
}

// ---------------------------------------------------------------------------
// One-shot weight convert: 5x [512x512] fp32 -> bf16, stored PRE-SWIZZLED so
// the GEMMs can global_load_lds them linearly and read with the XOR pattern:
//   dst[row][kc*64 + sj*8 + e] = src[row][kc*64 + (sj^(row&7))*8 + e]
// (XOR is an involution: linear DMA dest + inverse-swizzled source == swizzled
//  read, per the both-sides-or-neither rule.)
// 5*512*64 slots of 8 elems; 640 blocks x 256 threads, ~5 MB L2-resident.
// ---------------------------------------------------------------------------
struct WCvtArgs { const float* src[5]; unsigned short* dst[5]; };
__global__ __launch_bounds__(256) void cvt_w(WCvtArgs a) {
    const int gid = blockIdx.x * 256 + threadIdx.x;
    const int m = gid >> 15;                  // 32768 slots per matrix
    const int rem = gid & 32767;
    const int row = rem >> 6, c = rem & 63;
    const int kc = c >> 3, sjd = c & 7;
    const int sjs = sjd ^ (row & 7);
    const float* s = a.src[m] + row * 512 + kc * 64 + sjs * 8;
    const f32x4 v0 = *(const f32x4*)s;
    const f32x4 v1 = *(const f32x4*)(s + 4);
    u32x4 o;
    o[0] = pk2(v0[0], v0[1]);
    o[1] = pk2(v0[2], v0[3]);
    o[2] = pk2(v1[0], v1[1]);
    o[3] = pk2(v1[2], v1[3]);
    *(u32x4*)(a.dst[m] + row * 512 + kc * 64 + sjd * 8) = o;
}

// ---------------------------------------------------------------------------
// bf16 MFMA NT GEMM, K=512, tile 64x128, BK=64, 4 waves (each 32 rows x 64
// cols, acc[2][4] -> 16 MFMA per K-step per wave).
// B (weights): pre-swizzled bf16 in ws, staged via global_load_lds width=16
// (no registers, no cvt, no ds_write). A: fp32 (proj) reg-staged + cvt_pk +
// swizzled ds_write, or bf16 (FF) reg-staged. Double-buffered, 2 barriers/iter
// (stores for chunk kc issued after all waves finished reading buf; glds16
// drains at the next barrier's vmcnt(0)).
// IS_FF=false: grid (4,48,4), z selects {q,k,v,pe} epilogues, A fp32.
// IS_FF=true : grid (4,48,1), A=Obf (bf16), out = fp32 d_out + bias.
// ---------------------------------------------------------------------------
template <bool IS_FF>
__global__ __launch_bounds__(256) void gemm_nt(
    const float* __restrict__ A0, const float* __restrict__ A1,
    const float* __restrict__ A2, const float* __restrict__ A3,
    const unsigned short* __restrict__ Abf,
    const unsigned short* __restrict__ W0, const unsigned short* __restrict__ W1,
    const unsigned short* __restrict__ W2, const unsigned short* __restrict__ W3,
    const unsigned short* __restrict__ W4,
    const float* __restrict__ b0, const float* __restrict__ b1,
    const float* __restrict__ b2, const float* __restrict__ b3,
    const float* __restrict__ b4,
    const float* __restrict__ ub, const float* __restrict__ vbias,
    unsigned short* __restrict__ qu, unsigned short* __restrict__ qv,
    unsigned short* __restrict__ kb, unsigned short* __restrict__ vT,
    unsigned short* __restrict__ rp, float* __restrict__ ff) {

    const int z = IS_FF ? 4 : blockIdx.z;
    if (!IS_FF && z == 3 && blockIdx.y >= 12) return;   // pe: 768 rows only
    const float* Af   = z == 0 ? A0 : z == 1 ? A1 : z == 2 ? A2 : A3;
    const unsigned short* Wb =
        z == 0 ? W0 : z == 1 ? W1 : z == 2 ? W2 : z == 3 ? W3 : W4;
    const float* bias = z == 0 ? b0 : z == 1 ? b1 : z == 2 ? b2 : z == 3 ? b3 : b4;

    __shared__ __align__(16) unsigned short AsF[2 * 64 * 64];    // 16 KB
    __shared__ __align__(16) unsigned short BsF[2 * 128 * 64];   // 32 KB

    const int tid = threadIdx.x;
    const int w = tid >> 6, lane = tid & 63;
    const int quad = lane >> 4, lm = lane & 15;
    const int wr = (w & 1) * 32;          // wave row offset (A: 64 rows, 2x32)
    const int wc = (w >> 1) * 64;         // wave col offset (B: 128 rows, 2x64)

    // staging roles: lane covers (row sr in an 8-row group, k8 slot sj).
    // A: global read linear slot sj, LDS write slot sj^sr (swizzle-on-write).
    // B: source is PRE-swizzled, glds16 writes linearly (lane -> sr*64+sj*8).
    const int sr = lane >> 3, sj = lane & 7;
    const size_t aoff = (size_t)(blockIdx.y * 64 + w * 16 + sr) * 512 + sj * 8;
    const unsigned short* gB =
        Wb + (size_t)(blockIdx.x * 128 + w * 32 + sr) * 512 + sj * 8;

    f32x4 la[2][2];
    bf16x8 lah[2];

    auto LOAD_A = [&](int kc) {
        #pragma unroll
        for (int t = 0; t < 2; ++t) {
            if constexpr (IS_FF) {
                lah[t] = *(const bf16x8*)(Abf + aoff + t * 8 * 512 + kc * 64);
            } else {
                const float* p = Af + aoff + t * 8 * 512 + kc * 64;
                la[t][0] = *(const f32x4*)p;
                la[t][1] = *(const f32x4*)(p + 4);
            }
        }
    };
    auto WRITE_A = [&](int buf) {
        #pragma unroll
        for (int t = 0; t < 2; ++t) {
            const int off = buf * 4096 + (w * 16 + t * 8 + sr) * 64 + (sj ^ sr) * 8;
            if constexpr (IS_FF) {
                *(bf16x8*)&AsF[off] = lah[t];
            } else {
                u32x4 pa;
                pa[0] = pk2(la[t][0][0], la[t][0][1]);
                pa[1] = pk2(la[t][0][2], la[t][0][3]);
                pa[2] = pk2(la[t][1][0], la[t][1][1]);
                pa[3] = pk2(la[t][1][2], la[t][1][3]);
                *(u32x4*)&AsF[off] = pa;
            }
        }
    };
    auto STAGE_B = [&](int kc, int buf) {
        #pragma unroll
        for (int t = 0; t < 4; ++t) {
            int off = buf * 8192 + (w * 32 + t * 8) * 64;   // ushort index
            off = __builtin_amdgcn_readfirstlane(off);
            glds16(gB + t * 8 * 512 + kc * 64, &BsF[off]);
        }
    };

    f32x4 acc[2][4] = {};
    LOAD_A(0);
    for (int kc = 0; kc < 8; ++kc) {
        const int buf = kc & 1;
        WRITE_A(buf);                          // waits vmcnt for LOAD_A(kc)
        STAGE_B(kc, buf);                      // DMA, drains at next barrier
        if (kc < 7) LOAD_A(kc + 1);            // in flight across compute
        __syncthreads();
        const int ba = buf * 4096, bb = buf * 8192;
        #pragma unroll
        for (int ks = 0; ks < 2; ++ks) {
            const int s = (((ks * 4 + quad) ^ (lm & 7))) * 8;  // swizzled slot
            bf16x8 a0 = *(const bf16x8*)&AsF[ba + (wr + lm) * 64 + s];
            bf16x8 a1 = *(const bf16x8*)&AsF[ba + (wr + 16 + lm) * 64 + s];
            bf16x8 w0 = *(const bf16x8*)&BsF[bb + (wc + lm) * 64 + s];
            bf16x8 w1 = *(const bf16x8*)&BsF[bb + (wc + 16 + lm) * 64 + s];
            bf16x8 w2 = *(const bf16x8*)&BsF[bb + (wc + 32 + lm) * 64 + s];
            bf16x8 w3 = *(const bf16x8*)&BsF[bb + (wc + 48 + lm) * 64 + s];
            acc[0][0] = MFMA_BF16(a0, w0, acc[0][0], 0, 0, 0);
            acc[0][1] = MFMA_BF16(a0, w1, acc[0][1], 0, 0, 0);
            acc[0][2] = MFMA_BF16(a0, w2, acc[0][2], 0, 0, 0);
            acc[0][3] = MFMA_BF16(a0, w3, acc[0][3], 0, 0, 0);
            acc[1][0] = MFMA_BF16(a1, w0, acc[1][0], 0, 0, 0);
            acc[1][1] = MFMA_BF16(a1, w1, acc[1][1], 0, 0, 0);
            acc[1][2] = MFMA_BF16(a1, w2, acc[1][2], 0, 0, 0);
            acc[1][3] = MFMA_BF16(a1, w3, acc[1][3], 0, 0, 0);
        }
        __syncthreads();                       // buf reusable next iter
    }

    #pragma unroll
    for (int si = 0; si < 2; ++si) {
        #pragma unroll
        for (int sj2 = 0; sj2 < 4; ++sj2) {
            #pragma unroll
            for (int reg = 0; reg < 4; ++reg) {
                const int r = blockIdx.y * 64 + wr + si * 16 + quad * 4 + reg;
                const int c = blockIdx.x * 128 + wc + sj2 * 16 + lm;
                const float val = acc[si][sj2][reg] + bias[c];
                if (IS_FF) {
                    ff[r * 512 + c] = val;
                } else if (z == 0) {
                    const int bb2 = r / L_, ii = r - bb2 * L_;
                    const int h = c >> 6, d = c & 63;
                    const int idx = ((bb2 * NH_ + h) * L_ + ii) * DH_ + d;
                    qu[idx] = f2bf((val + ub[c]) * 0.125f);     // pow2 scale: exact
                    qv[idx] = f2bf((val + vbias[c]) * 0.125f);
                } else if (z == 1) {
                    const int bb2 = r / L_, ii = r - bb2 * L_;
                    const int h = c >> 6, d = c & 63;
                    kb[((bb2 * NH_ + h) * L_ + ii) * DH_ + d] = f2bf(val);
                } else if (z == 2) {
                    const int bb2 = r / L_, ii = r - bb2 * L_;
                    const int h = c >> 6, d = c & 63;
                    vT[((bb2 * NH_ + h) * DH_ + d) * L_ + ii] = f2bf(val);
                } else {
                    rp[r * 512 + c] = f2bf(val);
                }
            }
        }
    }
}

// ---------------------------------------------------------------------------
// Fully fused attention per (bh, 32-row i-tile)  [unchanged]
// ---------------------------------------------------------------------------
#define BTSTR 424
__global__ __launch_bounds__(256) void attn_fused(
    const unsigned short* __restrict__ qu, const unsigned short* __restrict__ qv,
    const unsigned short* __restrict__ kbf, const unsigned short* __restrict__ vT,
    const unsigned short* __restrict__ rp, const int* __restrict__ seq_len,
    unsigned short* __restrict__ Obf) {
    __shared__ __align__(16) unsigned short BtP[32 * BTSTR];
    __shared__ float mx_red[32][2];
    __shared__ float sm_red[32][2];
    const int lane = threadIdx.x & 63, wv = threadIdx.x >> 6;
    const int quad = lane >> 4, lm = lane & 15;
    const int bh = blockIdx.y, b = bh >> 3, h = bh & 7;
    const int i0 = blockIdx.x * 32;
    const int sl = seq_len[b];
    const int msub = wv & 1, nh = wv >> 1;
    const int m_lo = 353 - i0;
    const int i_fr = i0 + msub * 16 + lm;

    {
        const unsigned short* qvr = qv + (size_t)(bh * L_ + i_fr) * DH_;
        const bf16x8 av0 = *(const bf16x8*)(qvr + quad * 8);
        const bf16x8 av1 = *(const bf16x8*)(qvr + 32 + quad * 8);
        #pragma unroll
        for (int ns = 0; ns < 13; ++ns) {
            const int ntl = nh * 208 + ns * 16;
            if (ntl <= sl + 30) {
                const int n = ntl + lm;
                const unsigned short* rrow = rp + (size_t)(m_lo + n) * 512 + h * 64;
                f32x4 bacc = {};
                bacc = MFMA_BF16(av0, *(const bf16x8*)(rrow + quad * 8), bacc, 0, 0, 0);
                bacc = MFMA_BF16(av1, *(const bf16x8*)(rrow + 32 + quad * 8), bacc, 0, 0, 0);
                #pragma unroll
                for (int reg = 0; reg < 4; ++reg) {
                    const int il = msub * 16 + quad * 4 + reg;
                    BtP[il * BTSTR + n] = f2bf(bacc[reg]);
                }
            }
        }
    }
    const unsigned short* qur = qu + (size_t)(bh * L_ + i_fr) * DH_;
    const bf16x8 au0 = *(const bf16x8*)(qur + quad * 8);
    const bf16x8 au1 = *(const bf16x8*)(qur + 32 + quad * 8);
    __syncthreads();

    f32x4 sc[12];
    #pragma unroll
    for (int ns = 0; ns < 12; ++ns) {
        const int jt = nh * 192 + ns * 16;
        if (jt < sl) {
            const unsigned short* krow = kbf + (size_t)(bh * L_ + jt + lm) * DH_;
            f32x4 a = {};
            a = MFMA_BF16(au0, *(const bf16x8*)(krow + quad * 8), a, 0, 0, 0);
            a = MFMA_BF16(au1, *(const bf16x8*)(krow + 32 + quad * 8), a, 0, 0, 0);
            sc[ns] = a;
        } else {
            sc[ns] = f32x4{-1e30f, -1e30f, -1e30f, -1e30f};
        }
    }
    const int jbase = nh * 192 + lm;
    #pragma unroll
    for (int ns = 0; ns < 12; ++ns) {
        const int j = jbase + ns * 16;
        #pragma unroll
        for (int reg = 0; reg < 4; ++reg) {
            const int il = msub * 16 + quad * 4 + reg;
            float val = -1e30f;
            if (j < sl) val = sc[ns][reg] + bf2f(BtP[il * BTSTR + (j - il + 31)]);
            sc[ns][reg] = val;
        }
    }

    const int il0 = msub * 16 + quad * 4;
    float mx4[4], sm4[4], inv4[4];
    #pragma unroll
    for (int reg = 0; reg < 4; ++reg) {
        float m = sc[0][reg];
        #pragma unroll
        for (int ns = 1; ns < 12; ++ns) m = fmaxf(m, sc[ns][reg]);
        #pragma unroll
        for (int o = 1; o < 16; o <<= 1) m = fmaxf(m, __shfl_xor(m, o));
        mx4[reg] = m;
    }
    if (lm == 0) {
        #pragma unroll
        for (int reg = 0; reg < 4; ++reg) mx_red[il0 + reg][nh] = mx4[reg];
    }
    __syncthreads();
    #pragma unroll
    for (int reg = 0; reg < 4; ++reg)
        mx4[reg] = fmaxf(mx_red[il0 + reg][0], mx_red[il0 + reg][1]);
    #pragma unroll
    for (int reg = 0; reg < 4; ++reg) sm4[reg] = 0.f;
    #pragma unroll
    for (int ns = 0; ns < 12; ++ns) {
        #pragma unroll
        for (int reg = 0; reg < 4; ++reg) {
            const float e = __expf(sc[ns][reg] - mx4[reg]);
            sc[ns][reg] = e;
            sm4[reg] += e;
        }
    }
    #pragma unroll
    for (int reg = 0; reg < 4; ++reg) {
        float s = sm4[reg];
        #pragma unroll
        for (int o = 1; o < 16; o <<= 1) s += __shfl_xor(s, o);
        sm4[reg] = s;
    }
    if (lm == 0) {
        #pragma unroll
        for (int reg = 0; reg < 4; ++reg) sm_red[il0 + reg][nh] = sm4[reg];
    }
    __syncthreads();
    #pragma unroll
    for (int reg = 0; reg < 4; ++reg)
        inv4[reg] = 1.f / (sm_red[il0 + reg][0] + sm_red[il0 + reg][1]);

    #pragma unroll
    for (int ns = 0; ns < 12; ++ns) {
        const int j = jbase + ns * 16;
        #pragma unroll
        for (int reg = 0; reg < 4; ++reg)
            BtP[(il0 + reg) * BTSTR + j] = f2bf(sc[ns][reg] * inv4[reg]);
    }
    __syncthreads();

    {
        const int pr = msub * 16 + lm;
        const int nkc = (sl + 31) >> 5;
        f32x4 oacc[2] = {};
        for (int kc = 0; kc < nkc; ++kc) {
            const bf16x8 af = *(const bf16x8*)&BtP[pr * BTSTR + kc * 32 + quad * 8];
            #pragma unroll
            for (int t = 0; t < 2; ++t) {
                const int n = nh * 32 + t * 16 + lm;
                const unsigned short* vrow = vT + (size_t)(bh * DH_ + n) * L_ + kc * 32 + quad * 8;
                oacc[t] = MFMA_BF16(af, *(const bf16x8*)(vrow), oacc[t], 0, 0, 0);
            }
        }
        #pragma unroll
        for (int t = 0; t < 2; ++t) {
            #pragma unroll
            for (int reg = 0; reg < 4; ++reg) {
                const int i = i0 + msub * 16 + quad * 4 + reg;
                const int d = nh * 32 + t * 16 + lm;
                Obf[(size_t)(b * L_ + i) * H_ + h * DH_ + d] = f2bf(oacc[t][reg]);
            }
        }
    }
}

extern "C" void kernel_launch(void* const* d_in, const int* in_sizes, int n_in,
                              void* d_out, int out_size, void* d_ws, size_t ws_size,
                              hipStream_t stream) {
    const float* key    = (const float*)d_in[0];
    const float* query  = (const float*)d_in[1];
    const float* value  = (const float*)d_in[2];
    const int*   seqlen = (const int*)d_in[3];
    const float* pe     = (const float*)d_in[4];
    const float* Wk     = (const float*)d_in[5];
    const float* bk     = (const float*)d_in[6];
    const float* Wq     = (const float*)d_in[7];
    const float* bq     = (const float*)d_in[8];
    const float* Wv     = (const float*)d_in[9];
    const float* bv     = (const float*)d_in[10];
    const float* Wr     = (const float*)d_in[11];
    const float* br     = (const float*)d_in[12];
    const float* u_bias = (const float*)d_in[13];
    const float* v_bias = (const float*)d_in[14];
    const float* Wff    = (const float*)d_in[15];
    const float* bff    = (const float*)d_in[16];

    const size_t nTok = (size_t)B_ * L_ * H_;    // 1,572,864
    const size_t nPe  = (size_t)RRM * H_;        // 393,216
    const size_t nW   = (size_t)H_ * H_;         // 262,144
    unsigned short* p  = (unsigned short*)d_ws;
    unsigned short* qu   = p; p += nTok;
    unsigned short* qv   = p; p += nTok;
    unsigned short* kb   = p; p += nTok;
    unsigned short* vT   = p; p += nTok;
    unsigned short* rp   = p; p += nPe + 512;    // +1 pad row (corner n=415, never read back)
    unsigned short* Obf  = p; p += nTok;
    unsigned short* Wqb  = p; p += nW;           // pre-swizzled bf16 weights
    unsigned short* Wkb  = p; p += nW;
    unsigned short* Wvb  = p; p += nW;
    unsigned short* Wrb  = p; p += nW;
    unsigned short* Wffb = p; p += nW;

    // one-shot weight convert (5 MB, L2-resident, pre-swizzled for DMA staging)
    WCvtArgs wa;
    wa.src[0] = Wq;  wa.dst[0] = Wqb;
    wa.src[1] = Wk;  wa.dst[1] = Wkb;
    wa.src[2] = Wv;  wa.dst[2] = Wvb;
    wa.src[3] = Wr;  wa.dst[3] = Wrb;
    wa.src[4] = Wff; wa.dst[4] = Wffb;
    cvt_w<<<640, 256, 0, stream>>>(wa);

    // projections (fp32 A converted in-staging, bf16 W via global_load_lds):
    // u/v biases + 1/8 scale folded into q epilogue
    gemm_nt<false><<<dim3(4, 48, 4), 256, 0, stream>>>(
        /*A0..A3 fp32*/ query, key, value, pe, /*Abf*/ nullptr,
        /*W0..W4 bf16 preswz*/ Wqb, Wkb, Wvb, Wrb, nullptr,
        /*b0..b4*/ bq, bk, bv, br, nullptr,
        /*ub,vbias*/ u_bias, v_bias,
        /*qu,qv,kb,vT,rp*/ qu, qv, kb, vT, rp,
        /*ff*/ nullptr);

    // fused Bt + scores + softmax + PV
    attn_fused<<<dim3(L_ / 32, B_ * NH_), 256, 0, stream>>>(
        qu, qv, kb, vT, rp, seqlen, Obf);

    // output projection
    gemm_nt<true><<<dim3(4, 48, 1), 256, 0, stream>>>(
        /*A0..A3*/ nullptr, nullptr, nullptr, nullptr, /*Abf*/ Obf,
        /*W0..W4*/ nullptr, nullptr, nullptr, nullptr, Wffb,
        /*b0..b4*/ nullptr, nullptr, nullptr, nullptr, bff,
        /*ub,vbias*/ nullptr, nullptr,
        /*qu,qv,kb,vT,rp*/ nullptr, nullptr, nullptr, nullptr, nullptr,
        /*ff*/ (float*)d_out);
}